// Round 5
// baseline (62.562 us; speedup 1.0000x reference)
//
#include <hip/hip_runtime.h>

// Problem constants (from reference)
#define NRB 512
#define NTK 1024
#define DD  64
#define GHH 128

// Dead dataflow note: tgt = edge_index[1] + 512 in [512,1536) but robot_msgs =
// agg[:512] -> all-zero. Entire edge MLP + segment_sum is dead; output depends
// only on x_robot, x_task, Wv*, Wm*.  lrelu(x) = 0.55x + 0.45|x| (slope 0.1)
// factors the score into a[n] + c[m] + sum_h wb[h]*|HR[n,h]+HTB[m,h]|.
//
// Round-2 lesson: cooperative grid.sync ~60us/sync on MI355X -> kernel bounds.
// Round-3 lesson: 256 VGPR / 2 waves/SIMD -> latency-bound.
// Round-4 lesson: per-lane ROW reads of HTB (64 lines per wave instr) are the
// cost. Fix: HTB stored transposed [128 h][1024 m]; score stages 32-h chunks
// (128 KB) to LDS via coalesced linear float4 copy with register prefetch of
// the next chunk (T14); LDS reads lds[h*1024+tid] are 2-way-free on banks.

// Workspace layout (floats):
//   HR   [512][128]   @ 0        (row-major)
//   HTBt [128][1024]  @ 65536    (transposed, includes bm1)
//   a    [512]        @ 196608
//   c    [1024]       @ 197120
//   wb   [128]        @ 198144   (0.45 * Wm2)

// ---------------------------------------------------------------------------
// Kernel A: prep. Robot blocks (0..127): 4 robots each, 3-layer MLP ->
// HR[n][h] (row-major) and a[n]. Task blocks (128..383): 4 tasks each ->
// HTBt[h][m] = (x_task@Wm1[:,128:].T + bm1)^T and c[m].
// ---------------------------------------------------------------------------
__global__ __launch_bounds__(128) void prep_kernel(
    const float* __restrict__ xr, const float* __restrict__ xt,
    const float* __restrict__ Wv1, const float* __restrict__ bv1,
    const float* __restrict__ Wv2, const float* __restrict__ bv2,
    const float* __restrict__ Wm1, const float* __restrict__ bm1,
    const float* __restrict__ Wm2, const float* __restrict__ bm2,
    float* __restrict__ HR, float* __restrict__ HTBt,
    float* __restrict__ av, float* __restrict__ cv, float* __restrict__ wbv)
{
    const int i = threadIdx.x;      // 0..127
    __shared__ float xs[4][DD];     // 4 input rows
    __shared__ float sA[4][GHH];    // h1
    __shared__ float sB[4][GHH];    // h
    __shared__ float sR[4][GHH];    // reduction scratch
    __shared__ float sT[4][GHH + 1];// transpose scratch (task path)

    if (blockIdx.x < NRB / 4) {
        // -------- robot path --------
        const int r0 = blockIdx.x * 4;
        ((float*)xs)[i]       = xr[r0 * DD + i];
        ((float*)xs)[128 + i] = xr[r0 * DD + 128 + i];
        __syncthreads();

        // phase 1: h1[r][i] = lrelu(bv1[i] + x[r] . Wv1[i, 128:192])
        {
            float4 w[16];
            const float4* wp = reinterpret_cast<const float4*>(Wv1 + i * 192 + 128);
            #pragma unroll
            for (int q = 0; q < 16; ++q) w[q] = wp[q];
            const float b = bv1[i];
            for (int r = 0; r < 4; ++r) {
                float acc = b;
                #pragma unroll
                for (int q = 0; q < 16; ++q) {
                    acc = fmaf(w[q].x, xs[r][q*4+0], acc);
                    acc = fmaf(w[q].y, xs[r][q*4+1], acc);
                    acc = fmaf(w[q].z, xs[r][q*4+2], acc);
                    acc = fmaf(w[q].w, xs[r][q*4+3], acc);
                }
                sA[r][i] = (acc >= 0.f) ? acc : 0.1f * acc;
            }
        }
        __syncthreads();

        // phase 2: h[r][i] = bv2[i] + h1[r] . Wv2[i, :]
        {
            float4 w[32];
            const float4* wp = reinterpret_cast<const float4*>(Wv2 + i * GHH);
            #pragma unroll
            for (int q = 0; q < 32; ++q) w[q] = wp[q];
            const float b = bv2[i];
            for (int r = 0; r < 4; ++r) {
                float acc = b;
                const float4* hp = reinterpret_cast<const float4*>(sA[r]);
                #pragma unroll
                for (int q = 0; q < 32; ++q) {
                    float4 h4 = hp[q];
                    acc = fmaf(w[q].x, h4.x, acc);
                    acc = fmaf(w[q].y, h4.y, acc);
                    acc = fmaf(w[q].z, h4.z, acc);
                    acc = fmaf(w[q].w, h4.w, acc);
                }
                sB[r][i] = acc;   // no activation on h
            }
        }
        __syncthreads();

        // phase 3: hr[r][i] = h[r] . Wm1[i, :128];  a[n] = 0.55 * sum w*hr
        {
            float4 w[32];
            const float4* wp = reinterpret_cast<const float4*>(Wm1 + i * 192);
            #pragma unroll
            for (int q = 0; q < 32; ++q) w[q] = wp[q];
            const float wm2 = Wm2[i];
            for (int r = 0; r < 4; ++r) {
                float acc = 0.f;
                const float4* hp = reinterpret_cast<const float4*>(sB[r]);
                #pragma unroll
                for (int q = 0; q < 32; ++q) {
                    float4 h4 = hp[q];
                    acc = fmaf(w[q].x, h4.x, acc);
                    acc = fmaf(w[q].y, h4.y, acc);
                    acc = fmaf(w[q].z, h4.z, acc);
                    acc = fmaf(w[q].w, h4.w, acc);
                }
                HR[(r0 + r) * GHH + i] = acc;
                sR[r][i] = wm2 * acc;
            }
        }
        __syncthreads();
        {
            const int r = i >> 5, c = i & 31;
            float s = sR[r][c] + sR[r][c+32] + sR[r][c+64] + sR[r][c+96];
            #pragma unroll
            for (int off = 16; off >= 1; off >>= 1) s += __shfl_xor(s, off, 32);
            if (c == 0) av[r0 + r] = 0.55f * s;
        }
    } else {
        // -------- task path --------
        const int t0 = (blockIdx.x - NRB / 4) * 4;
        ((float*)xs)[i]       = xt[t0 * DD + i];
        ((float*)xs)[128 + i] = xt[t0 * DD + 128 + i];
        __syncthreads();

        float4 w[16];
        const float4* wp = reinterpret_cast<const float4*>(Wm1 + i * 192 + 128);
        #pragma unroll
        for (int q = 0; q < 16; ++q) w[q] = wp[q];
        const float b   = bm1[i];
        const float wm2 = Wm2[i];
        for (int t = 0; t < 4; ++t) {
            float acc = b;
            #pragma unroll
            for (int q = 0; q < 16; ++q) {
                acc = fmaf(w[q].x, xs[t][q*4+0], acc);
                acc = fmaf(w[q].y, xs[t][q*4+1], acc);
                acc = fmaf(w[q].z, xs[t][q*4+2], acc);
                acc = fmaf(w[q].w, xs[t][q*4+3], acc);
            }
            sT[t][i]  = acc;          // includes bm1; staged for transpose
            sR[t][i]  = wm2 * acc;
        }
        __syncthreads();

        // transposed write: HTBt[h][t0+m], 512 elems, m fastest for coalescing
        #pragma unroll
        for (int k = 0; k < 4; ++k) {
            const int wdx = i + k * 128;       // 0..511
            const int h   = wdx >> 2;
            const int m   = wdx & 3;
            HTBt[h * NTK + t0 + m] = sT[m][h];
        }
        {
            const int r = i >> 5, c = i & 31;
            float s = sR[r][c] + sR[r][c+32] + sR[r][c+64] + sR[r][c+96];
            #pragma unroll
            for (int off = 16; off >= 1; off >>= 1) s += __shfl_xor(s, off, 32);
            if (c == 0) cv[t0 + r] = 0.55f * s + bm2[0];
        }
        if (blockIdx.x == NRB / 4) wbv[i] = 0.45f * wm2;
    }
}

// ---------------------------------------------------------------------------
// Kernel B: fused score + softmax. 256 blocks x 1024 threads; block b owns
// rows n0=2b,2b+1; thread tid owns column m=tid. HTBt staged per 32-h chunk
// (128 KB) into LDS via coalesced linear float4 copy; next chunk prefetched
// into registers during compute (T14). LDS reads 2-way-free. hr/wb are
// block-uniform -> scalar loads. Then block-local softmax, coalesced store.
// ---------------------------------------------------------------------------
__global__ __launch_bounds__(1024) void score_softmax_kernel(
    const float* __restrict__ HR, const float* __restrict__ HTBt,
    const float* __restrict__ av, const float* __restrict__ cv,
    const float* __restrict__ wbv, float* __restrict__ out)
{
    __shared__ float lds[32 * 1024];           // 128 KB, one chunk
    const int b   = blockIdx.x;                // 0..255
    const int tid = threadIdx.x;               // 0..1023 == m
    const int n0  = b * 2;

    const float4* src   = reinterpret_cast<const float4*>(HTBt);
    float4*       ldsf4 = reinterpret_cast<float4*>(lds);

    // prologue: chunk 0 -> regs
    float4 r[8];
    #pragma unroll
    for (int k = 0; k < 8; ++k) r[k] = src[k * 1024 + tid];

    const float* hr0 = HR + n0 * GHH;
    const float* hr1 = HR + (n0 + 1) * GHH;

    float acc0 = 0.f, acc1 = 0.f;

    #pragma unroll 1
    for (int c = 0; c < 4; ++c) {
        __syncthreads();                       // lds consumers done
        #pragma unroll
        for (int k = 0; k < 8; ++k) ldsf4[k * 1024 + tid] = r[k];
        if (c < 3) {
            #pragma unroll
            for (int k = 0; k < 8; ++k)
                r[k] = src[(c + 1) * 8192 + k * 1024 + tid];
        }
        __syncthreads();                       // chunk staged

        #pragma unroll
        for (int h = 0; h < 32; ++h) {
            const int hh = c * 32 + h;
            const float tb = lds[h * 1024 + tid];
            const float w  = wbv[hh];
            const float x0 = hr0[hh] + tb;
            const float x1 = hr1[hh] + tb;
            acc0 = fmaf(w, fabsf(x0), acc0);
            acc1 = fmaf(w, fabsf(x1), acc1);
        }
    }

    const float cm = cv[tid];
    float sc[2];
    sc[0] = acc0 + av[n0]     + cm;
    sc[1] = acc1 + av[n0 + 1] + cm;

    // ---- block-local softmax over the 1024 columns, both rows ----
    __shared__ float rmax[2][16], rsum[2][16];
    const int wid = tid >> 6, lane = tid & 63;

    #pragma unroll
    for (int n = 0; n < 2; ++n) {
        float mx = sc[n];
        #pragma unroll
        for (int off = 32; off >= 1; off >>= 1)
            mx = fmaxf(mx, __shfl_xor(mx, off, 64));
        if (lane == 0) rmax[n][wid] = mx;
    }
    __syncthreads();

    float ex[2];
    #pragma unroll
    for (int n = 0; n < 2; ++n) {
        float mx = rmax[n][0];
        #pragma unroll
        for (int k = 1; k < 16; ++k) mx = fmaxf(mx, rmax[n][k]);
        float e = expf(sc[n] - mx);
        ex[n] = e;
        float s = e;
        #pragma unroll
        for (int off = 32; off >= 1; off >>= 1) s += __shfl_xor(s, off, 64);
        if (lane == 0) rsum[n][wid] = s;
    }
    __syncthreads();

    #pragma unroll
    for (int n = 0; n < 2; ++n) {
        float s = rsum[n][0];
        #pragma unroll
        for (int k = 1; k < 16; ++k) s += rsum[n][k];
        out[(n0 + n) * NTK + tid] = ex[n] * (1.0f / s);
    }
}

extern "C" void kernel_launch(void* const* d_in, const int* in_sizes, int n_in,
                              void* d_out, int out_size, void* d_ws, size_t ws_size,
                              hipStream_t stream)
{
    const float* xr  = (const float*)d_in[0];
    const float* xt  = (const float*)d_in[1];
    // d_in[2]=edge_index, [3]=edge_attr, [4..7]=We1,be1,We2,be2 : provably dead
    const float* Wv1 = (const float*)d_in[8];
    const float* bv1 = (const float*)d_in[9];
    const float* Wv2 = (const float*)d_in[10];
    const float* bv2 = (const float*)d_in[11];
    const float* Wm1 = (const float*)d_in[12];
    const float* bm1 = (const float*)d_in[13];
    const float* Wm2 = (const float*)d_in[14];
    const float* bm2 = (const float*)d_in[15];

    float* ws   = (float*)d_ws;
    float* HR   = ws;
    float* HTBt = ws + 65536;
    float* av   = ws + 196608;
    float* cv   = ws + 197120;
    float* wbv  = ws + 198144;
    float* out  = (float*)d_out;

    hipLaunchKernelGGL(prep_kernel, dim3(384), dim3(128), 0, stream,
                       xr, xt, Wv1, bv1, Wv2, bv2, Wm1, bm1, Wm2, bm2,
                       HR, HTBt, av, cv, wbv);
    hipLaunchKernelGGL(score_softmax_kernel, dim3(256), dim3(1024), 0, stream,
                       HR, HTBt, av, cv, wbv, out);
}

// Round 6
// 26.056 us; speedup vs baseline: 2.4010x; 2.4010x over previous
//
#include <hip/hip_runtime.h>

// Problem constants (from reference)
#define NRB 512
#define NTK 1024
#define DD  64
#define GHH 128

// Dead dataflow note: tgt = edge_index[1] + 512 in [512,1536) but robot_msgs =
// agg[:512] -> all-zero. Entire edge MLP + segment_sum is dead; output depends
// only on x_robot, x_task, Wv*, Wm*.  lrelu(x) = 0.55x + 0.45|x| (slope 0.1)
// factors the score into a[n] + c[m] + sum_h wb[h]*|HR[n,h]+HTB[m,h]|.
//
// Round-2 lesson: cooperative grid.sync ~60us/sync on MI355X -> kernel bounds.
// Round-3 lesson: 256 VGPR / 2 waves/SIMD -> latency-bound.
// Round-4 lesson: per-lane ROW reads (64 lines/wave-instr) are the cost ->
// HTBt stored transposed [128 h][1024 m] so column reads coalesce.
// Round-5 lesson: float4 r[8] register staging spilled to scratch (VGPR=52,
// WRITE_SIZE 133MB = 4 x 33.5MB spill writes). NO register/LDS staging --
// direct coalesced dword loads, ~25 VGPR, nothing to spill.

// Workspace layout (floats):
//   HR   [512][128]   @ 0        (row-major)
//   HTBt [128][1024]  @ 65536    (transposed, includes bm1)
//   a    [512]        @ 196608
//   c    [1024]       @ 197120
//   wb   [128]        @ 198144   (0.45 * Wm2)

// ---------------------------------------------------------------------------
// Kernel A: prep. Robot blocks (0..127): 4 robots each, 3-layer MLP ->
// HR[n][h] (row-major) and a[n]. Task blocks (128..383): 4 tasks each ->
// HTBt[h][m] = (x_task@Wm1[:,128:].T + bm1)^T and c[m].
// ---------------------------------------------------------------------------
__global__ __launch_bounds__(128) void prep_kernel(
    const float* __restrict__ xr, const float* __restrict__ xt,
    const float* __restrict__ Wv1, const float* __restrict__ bv1,
    const float* __restrict__ Wv2, const float* __restrict__ bv2,
    const float* __restrict__ Wm1, const float* __restrict__ bm1,
    const float* __restrict__ Wm2, const float* __restrict__ bm2,
    float* __restrict__ HR, float* __restrict__ HTBt,
    float* __restrict__ av, float* __restrict__ cv, float* __restrict__ wbv)
{
    const int i = threadIdx.x;      // 0..127
    __shared__ float xs[4][DD];     // 4 input rows
    __shared__ float sA[4][GHH];    // h1
    __shared__ float sB[4][GHH];    // h
    __shared__ float sR[4][GHH];    // reduction scratch
    __shared__ float sT[4][GHH + 1];// transpose scratch (task path)

    if (blockIdx.x < NRB / 4) {
        // -------- robot path --------
        const int r0 = blockIdx.x * 4;
        ((float*)xs)[i]       = xr[r0 * DD + i];
        ((float*)xs)[128 + i] = xr[r0 * DD + 128 + i];
        __syncthreads();

        // phase 1: h1[r][i] = lrelu(bv1[i] + x[r] . Wv1[i, 128:192])
        {
            float4 w[16];
            const float4* wp = reinterpret_cast<const float4*>(Wv1 + i * 192 + 128);
            #pragma unroll
            for (int q = 0; q < 16; ++q) w[q] = wp[q];
            const float b = bv1[i];
            for (int r = 0; r < 4; ++r) {
                float acc = b;
                #pragma unroll
                for (int q = 0; q < 16; ++q) {
                    acc = fmaf(w[q].x, xs[r][q*4+0], acc);
                    acc = fmaf(w[q].y, xs[r][q*4+1], acc);
                    acc = fmaf(w[q].z, xs[r][q*4+2], acc);
                    acc = fmaf(w[q].w, xs[r][q*4+3], acc);
                }
                sA[r][i] = (acc >= 0.f) ? acc : 0.1f * acc;
            }
        }
        __syncthreads();

        // phase 2: h[r][i] = bv2[i] + h1[r] . Wv2[i, :]
        {
            float4 w[32];
            const float4* wp = reinterpret_cast<const float4*>(Wv2 + i * GHH);
            #pragma unroll
            for (int q = 0; q < 32; ++q) w[q] = wp[q];
            const float b = bv2[i];
            for (int r = 0; r < 4; ++r) {
                float acc = b;
                const float4* hp = reinterpret_cast<const float4*>(sA[r]);
                #pragma unroll
                for (int q = 0; q < 32; ++q) {
                    float4 h4 = hp[q];
                    acc = fmaf(w[q].x, h4.x, acc);
                    acc = fmaf(w[q].y, h4.y, acc);
                    acc = fmaf(w[q].z, h4.z, acc);
                    acc = fmaf(w[q].w, h4.w, acc);
                }
                sB[r][i] = acc;   // no activation on h
            }
        }
        __syncthreads();

        // phase 3: hr[r][i] = h[r] . Wm1[i, :128];  a[n] = 0.55 * sum w*hr
        {
            float4 w[32];
            const float4* wp = reinterpret_cast<const float4*>(Wm1 + i * 192);
            #pragma unroll
            for (int q = 0; q < 32; ++q) w[q] = wp[q];
            const float wm2 = Wm2[i];
            for (int r = 0; r < 4; ++r) {
                float acc = 0.f;
                const float4* hp = reinterpret_cast<const float4*>(sB[r]);
                #pragma unroll
                for (int q = 0; q < 32; ++q) {
                    float4 h4 = hp[q];
                    acc = fmaf(w[q].x, h4.x, acc);
                    acc = fmaf(w[q].y, h4.y, acc);
                    acc = fmaf(w[q].z, h4.z, acc);
                    acc = fmaf(w[q].w, h4.w, acc);
                }
                HR[(r0 + r) * GHH + i] = acc;
                sR[r][i] = wm2 * acc;
            }
        }
        __syncthreads();
        {
            const int r = i >> 5, c = i & 31;
            float s = sR[r][c] + sR[r][c+32] + sR[r][c+64] + sR[r][c+96];
            #pragma unroll
            for (int off = 16; off >= 1; off >>= 1) s += __shfl_xor(s, off, 32);
            if (c == 0) av[r0 + r] = 0.55f * s;
        }
    } else {
        // -------- task path --------
        const int t0 = (blockIdx.x - NRB / 4) * 4;
        ((float*)xs)[i]       = xt[t0 * DD + i];
        ((float*)xs)[128 + i] = xt[t0 * DD + 128 + i];
        __syncthreads();

        float4 w[16];
        const float4* wp = reinterpret_cast<const float4*>(Wm1 + i * 192 + 128);
        #pragma unroll
        for (int q = 0; q < 16; ++q) w[q] = wp[q];
        const float b   = bm1[i];
        const float wm2 = Wm2[i];
        for (int t = 0; t < 4; ++t) {
            float acc = b;
            #pragma unroll
            for (int q = 0; q < 16; ++q) {
                acc = fmaf(w[q].x, xs[t][q*4+0], acc);
                acc = fmaf(w[q].y, xs[t][q*4+1], acc);
                acc = fmaf(w[q].z, xs[t][q*4+2], acc);
                acc = fmaf(w[q].w, xs[t][q*4+3], acc);
            }
            sT[t][i]  = acc;          // includes bm1; staged for transpose
            sR[t][i]  = wm2 * acc;
        }
        __syncthreads();

        // transposed write: HTBt[h][t0+m], 512 elems, m fastest
        #pragma unroll
        for (int k = 0; k < 4; ++k) {
            const int wdx = i + k * 128;       // 0..511
            const int h   = wdx >> 2;
            const int m   = wdx & 3;
            HTBt[h * NTK + t0 + m] = sT[m][h];
        }
        {
            const int r = i >> 5, c = i & 31;
            float s = sR[r][c] + sR[r][c+32] + sR[r][c+64] + sR[r][c+96];
            #pragma unroll
            for (int off = 16; off >= 1; off >>= 1) s += __shfl_xor(s, off, 32);
            if (c == 0) cv[t0 + r] = 0.55f * s + bm2[0];
        }
        if (blockIdx.x == NRB / 4) wbv[i] = 0.45f * wm2;
    }
}

// ---------------------------------------------------------------------------
// Kernel B: fused score + softmax. 256 blocks x 1024 threads (16 waves/CU,
// 4/SIMD). Block b owns rows n0=2b,2b+1; thread tid owns column m=tid.
// Per h: ONE coalesced dword load of HTBt[h][tid] (wave reads 256B
// contiguous); hr0/hr1/wb are wave-uniform -> scalar loads; 4 VALU.
// No staging arrays -> nothing to spill (round-5 lesson). Then block-local
// softmax per row, coalesced store.
// ---------------------------------------------------------------------------
__global__ __launch_bounds__(1024) void score_softmax_kernel(
    const float* __restrict__ HR, const float* __restrict__ HTBt,
    const float* __restrict__ av, const float* __restrict__ cv,
    const float* __restrict__ wbv, float* __restrict__ out)
{
    const int b   = blockIdx.x;     // 0..255
    const int tid = threadIdx.x;    // 0..1023 == m
    const int n0  = b * 2;

    const float* hr0 = HR + n0 * GHH;
    const float* hr1 = hr0 + GHH;
    const float* tbp = HTBt + tid;

    float acc0 = 0.f, acc1 = 0.f;

    #pragma unroll 8
    for (int h = 0; h < 128; ++h) {
        const float tb = tbp[h * NTK];   // coalesced across lanes
        const float w  = wbv[h];         // uniform -> s_load
        const float r0 = hr0[h];
        const float r1 = hr1[h];
        acc0 = fmaf(w, fabsf(r0 + tb), acc0);
        acc1 = fmaf(w, fabsf(r1 + tb), acc1);
    }

    const float cm = cv[tid];
    float sc[2];
    sc[0] = acc0 + av[n0]     + cm;
    sc[1] = acc1 + av[n0 + 1] + cm;

    // ---- block-local softmax over the 1024 columns, both rows ----
    __shared__ float rmax[2][16], rsum[2][16];
    const int wid = tid >> 6, lane = tid & 63;

    #pragma unroll
    for (int n = 0; n < 2; ++n) {
        float mx = sc[n];
        #pragma unroll
        for (int off = 32; off >= 1; off >>= 1)
            mx = fmaxf(mx, __shfl_xor(mx, off, 64));
        if (lane == 0) rmax[n][wid] = mx;
    }
    __syncthreads();

    float ex[2];
    #pragma unroll
    for (int n = 0; n < 2; ++n) {
        float mx = rmax[n][0];
        #pragma unroll
        for (int k = 1; k < 16; ++k) mx = fmaxf(mx, rmax[n][k]);
        float e = expf(sc[n] - mx);
        ex[n] = e;
        float s = e;
        #pragma unroll
        for (int off = 32; off >= 1; off >>= 1) s += __shfl_xor(s, off, 64);
        if (lane == 0) rsum[n][wid] = s;
    }
    __syncthreads();

    #pragma unroll
    for (int n = 0; n < 2; ++n) {
        float s = rsum[n][0];
        #pragma unroll
        for (int k = 1; k < 16; ++k) s += rsum[n][k];
        out[(n0 + n) * NTK + tid] = ex[n] * (1.0f / s);
    }
}

extern "C" void kernel_launch(void* const* d_in, const int* in_sizes, int n_in,
                              void* d_out, int out_size, void* d_ws, size_t ws_size,
                              hipStream_t stream)
{
    const float* xr  = (const float*)d_in[0];
    const float* xt  = (const float*)d_in[1];
    // d_in[2]=edge_index, [3]=edge_attr, [4..7]=We1,be1,We2,be2 : provably dead
    const float* Wv1 = (const float*)d_in[8];
    const float* bv1 = (const float*)d_in[9];
    const float* Wv2 = (const float*)d_in[10];
    const float* bv2 = (const float*)d_in[11];
    const float* Wm1 = (const float*)d_in[12];
    const float* bm1 = (const float*)d_in[13];
    const float* Wm2 = (const float*)d_in[14];
    const float* bm2 = (const float*)d_in[15];

    float* ws   = (float*)d_ws;
    float* HR   = ws;
    float* HTBt = ws + 65536;
    float* av   = ws + 196608;
    float* cv   = ws + 197120;
    float* wbv  = ws + 198144;
    float* out  = (float*)d_out;

    hipLaunchKernelGGL(prep_kernel, dim3(384), dim3(128), 0, stream,
                       xr, xt, Wv1, bv1, Wv2, bv2, Wm1, bm1, Wm2, bm2,
                       HR, HTBt, av, cv, wbv);
    hipLaunchKernelGGL(score_softmax_kernel, dim3(256), dim3(1024), 0, stream,
                       HR, HTBt, av, cv, wbv, out);
}